// Round 1
// 60.381 us; speedup vs baseline: 1.0258x; 1.0258x over previous
//
#include <hip/hip_runtime.h>

// Two batch elements per thread, packed in float2 ext-vectors so the backend can
// select VOP3P v_pk_{mul,add,fma}_f32 (one issue slot per 2 elements) and so the
// 16 batch-uniform __sincosf of params are amortized across both elements.
typedef float v2f __attribute__((ext_vector_type(2)));

// Flattened state index: idx = b0*8 + b1*4 + b2*2 + b3  (qubit q -> bit (3-q))
template<int Q>
__device__ __forceinline__ void apply_ry(v2f (&sr)[16], v2f (&si)[16], float c, float s) {
    constexpr int m = 1 << (3 - Q);
    #pragma unroll
    for (int idx = 0; idx < 16; ++idx) {
        if (!(idx & m)) {
            const int j = idx | m;
            v2f ar = sr[idx], ai = si[idx], br = sr[j], bi = si[j];
            sr[idx] = c * ar - s * br;  si[idx] = c * ai - s * bi;
            sr[j]   = s * ar + c * br;  si[j]   = s * ai + c * bi;
        }
    }
}
// RZ(theta): bit==0 amp *= (c - i s), bit==1 amp *= (c + i s)   [c,s of theta/2]
template<int Q>
__device__ __forceinline__ void apply_rz(v2f (&sr)[16], v2f (&si)[16], float c, float s) {
    constexpr int m = 1 << (3 - Q);
    #pragma unroll
    for (int idx = 0; idx < 16; ++idx) {
        v2f r = sr[idx], i_ = si[idx];
        if (idx & m) { sr[idx] = c * r - s * i_;  si[idx] = c * i_ + s * r; }
        else         { sr[idx] = c * r + s * i_;  si[idx] = c * i_ - s * r; }
    }
}
template<int C, int T>
__device__ __forceinline__ void apply_cnot(v2f (&sr)[16], v2f (&si)[16]) {
    constexpr int mc = 1 << (3 - C), mt = 1 << (3 - T);
    #pragma unroll
    for (int idx = 0; idx < 16; ++idx) {
        if ((idx & mc) && !(idx & mt)) {
            const int j = idx | mt;
            v2f tr = sr[idx], ti = si[idx];
            sr[idx] = sr[j];  si[idx] = si[j];
            sr[j] = tr;       si[j] = ti;
        }
    }
}

__global__ __launch_bounds__(256) void qsim_kernel(const float* __restrict__ x,
                                                   const float* __restrict__ params,
                                                   float* __restrict__ out, int n) {
    const int t = blockIdx.x * blockDim.x + threadIdx.x;
    const int b0 = t * 2;
    if (b0 >= n) return;
    const int b1 = (b0 + 1 < n) ? b0 + 1 : b0;   // n is even in practice; safe clamp

    // ---- uniform (batch-independent) trig, computed ONCE per thread (scalar) ----
    // params[l*12 + i*3 + {0:ry, 1:rz, 2:unused}]
    float cf[4], sf[4];          // layer-1 RZ, FULL angle (global phase factored out)
    float c1y[4], s1y[4];        // layer-2 RY half-angle
    float c1z[4], s1z[4];        // layer-2 RZ half-angle
    float c2y[4], s2y[4];        // layer-3 RY half-angle (layer-3 RZ dropped: phases
                                 // before pure permutations + |amp|^2 are unobservable)
    #pragma unroll
    for (int i = 0; i < 4; ++i) {
        __sincosf(params[0 * 12 + i * 3 + 1],        &sf[i],  &cf[i]);
        __sincosf(0.5f * params[1 * 12 + i * 3 + 0], &s1y[i], &c1y[i]);
        __sincosf(0.5f * params[1 * 12 + i * 3 + 1], &s1z[i], &c1z[i]);
        __sincosf(0.5f * params[2 * 12 + i * 3 + 0], &s2y[i], &c2y[i]);
    }

    // ---- layer 1 encoding: RY(x_i + theta_ry), RZ as per-qubit phase ----
    const float4 xa = reinterpret_cast<const float4*>(x)[b0];
    const float4 xb = reinterpret_cast<const float4*>(x)[b1];

    v2f cy[4], sy[4];
    {
        const float th0 = params[0 * 12 + 0 * 3 + 0];
        const float th1 = params[0 * 12 + 1 * 3 + 0];
        const float th2 = params[0 * 12 + 2 * 3 + 0];
        const float th3 = params[0 * 12 + 3 * 3 + 0];
        float ca, sa, cb, sb;
        __sincosf(0.5f * (xa.x + th0), &sa, &ca);  __sincosf(0.5f * (xb.x + th0), &sb, &cb);
        cy[0] = (v2f){ca, cb};  sy[0] = (v2f){sa, sb};
        __sincosf(0.5f * (xa.y + th1), &sa, &ca);  __sincosf(0.5f * (xb.y + th1), &sb, &cb);
        cy[1] = (v2f){ca, cb};  sy[1] = (v2f){sa, sb};
        __sincosf(0.5f * (xa.z + th2), &sa, &ca);  __sincosf(0.5f * (xb.z + th2), &sb, &cb);
        cy[2] = (v2f){ca, cb};  sy[2] = (v2f){sa, sb};
        __sincosf(0.5f * (xa.w + th3), &sa, &ca);  __sincosf(0.5f * (xb.w + th3), &sb, &cb);
        cy[3] = (v2f){ca, cb};  sy[3] = (v2f){sa, sb};
    }

    // qubit i post-layer-1 vector (global phase dropped): v0 = cos(a_i) real, v1 = sin(a_i) e^{i phi_i}
    v2f v1r[4], v1i[4];
    #pragma unroll
    for (int i = 0; i < 4; ++i) { v1r[i] = sy[i] * cf[i]; v1i[i] = sy[i] * sf[i]; }

    // pair tensor products: P = q0 (x) q1, Q = q2 (x) q3   (component 0 of each qubit real)
    const v2f zero = (v2f){0.0f, 0.0f};
    v2f pr[4], pi_[4], qr[4], qi[4];
    pr[0] = cy[0] * cy[1];                          pi_[0] = zero;
    pr[1] = cy[0] * v1r[1];                         pi_[1] = cy[0] * v1i[1];
    pr[2] = v1r[0] * cy[1];                         pi_[2] = v1i[0] * cy[1];
    pr[3] = v1r[0] * v1r[1] - v1i[0] * v1i[1];      pi_[3] = v1r[0] * v1i[1] + v1i[0] * v1r[1];
    qr[0] = cy[2] * cy[3];                          qi[0] = zero;
    qr[1] = cy[2] * v1r[3];                         qi[1] = cy[2] * v1i[3];
    qr[2] = v1r[2] * cy[3];                         qi[2] = v1i[2] * cy[3];
    qr[3] = v1r[2] * v1r[3] - v1i[2] * v1i[3];      qi[3] = v1r[2] * v1i[3] + v1i[2] * v1r[3];

    // full state after layer-1 single-qubit gates: state[p*4+q] = P[p] * Q[q]
    v2f sr[16], si[16];
    #pragma unroll
    for (int p = 0; p < 4; ++p)
        #pragma unroll
        for (int q = 0; q < 4; ++q) {
            sr[p * 4 + q] = pr[p] * qr[q] - pi_[p] * qi[q];
            si[p * 4 + q] = pr[p] * qi[q] + pi_[p] * qr[q];
        }

    // layer-1 CNOT chain (register permutation, no instructions)
    apply_cnot<0, 1>(sr, si);
    apply_cnot<1, 2>(sr, si);
    apply_cnot<2, 3>(sr, si);

    // ---- layer 2: full RY + RZ on each qubit, then CNOT chain ----
    apply_ry<0>(sr, si, c1y[0], s1y[0]);  apply_rz<0>(sr, si, c1z[0], s1z[0]);
    apply_ry<1>(sr, si, c1y[1], s1y[1]);  apply_rz<1>(sr, si, c1z[1], s1z[1]);
    apply_ry<2>(sr, si, c1y[2], s1y[2]);  apply_rz<2>(sr, si, c1z[2], s1z[2]);
    apply_ry<3>(sr, si, c1y[3], s1y[3]);  apply_rz<3>(sr, si, c1z[3], s1z[3]);
    apply_cnot<0, 1>(sr, si);
    apply_cnot<1, 2>(sr, si);
    apply_cnot<2, 3>(sr, si);

    // ---- layer 3: RY only (RZ unobservable), CNOT chain ----
    apply_ry<0>(sr, si, c2y[0], s2y[0]);
    apply_ry<1>(sr, si, c2y[1], s2y[1]);
    apply_ry<2>(sr, si, c2y[2], s2y[2]);
    apply_ry<3>(sr, si, c2y[3], s2y[3]);
    apply_cnot<0, 1>(sr, si);
    apply_cnot<1, 2>(sr, si);
    apply_cnot<2, 3>(sr, si);

    // ---- <Z_q> via tree-structured signed sums ----
    v2f p16[16];
    #pragma unroll
    for (int i = 0; i < 16; ++i) p16[i] = sr[i] * sr[i] + si[i] * si[i];
    v2f s8[8], d8[8];
    #pragma unroll
    for (int i = 0; i < 8; ++i) { s8[i] = p16[2 * i] + p16[2 * i + 1];
                                  d8[i] = p16[2 * i] - p16[2 * i + 1]; }
    v2f z3 = (d8[0] + d8[1]) + (d8[2] + d8[3]) + ((d8[4] + d8[5]) + (d8[6] + d8[7]));
    v2f z2 = (s8[0] - s8[1]) + (s8[2] - s8[3]) + ((s8[4] - s8[5]) + (s8[6] - s8[7]));
    v2f t4[4];
    #pragma unroll
    for (int i = 0; i < 4; ++i) t4[i] = s8[2 * i] + s8[2 * i + 1];
    v2f z1 = (t4[0] - t4[1]) + (t4[2] - t4[3]);
    v2f z0 = (t4[0] + t4[1]) - (t4[2] + t4[3]);

    float4 oa;  oa.x = z0.x;  oa.y = z1.x;  oa.z = z2.x;  oa.w = z3.x;
    reinterpret_cast<float4*>(out)[b0] = oa;
    if (b1 != b0) {
        float4 ob;  ob.x = z0.y;  ob.y = z1.y;  ob.z = z2.y;  ob.w = z3.y;
        reinterpret_cast<float4*>(out)[b1] = ob;
    }
}

extern "C" void kernel_launch(void* const* d_in, const int* in_sizes, int n_in,
                              void* d_out, int out_size, void* d_ws, size_t ws_size,
                              hipStream_t stream) {
    const float* x      = (const float*)d_in[0];   // (B,4) f32
    const float* params = (const float*)d_in[1];   // (3,4,3) f32
    float* out          = (float*)d_out;           // (B,4) f32
    int n = in_sizes[0] / 4;
    int threads = (n + 1) / 2;                     // 2 batch elements per thread
    int blocks = (threads + 255) / 256;
    hipLaunchKernelGGL(qsim_kernel, dim3(blocks), dim3(256), 0, stream, x, params, out, n);
}